// Round 21
// baseline (2906.396 us; speedup 1.0000x reference)
//
#include <hip/hip_runtime.h>
#include <hip/hip_bf16.h>
#include <stdint.h>

#define NPTS 2048
#define MB_ROW 256L
#define MB_B   ((long)NPTS * MB_ROW)
#define MB_T   (2 * MB_B)

typedef __attribute__((ext_vector_type(8))) short bf16x8;
typedef __attribute__((ext_vector_type(4))) float f32x4;
#define MFMA16 __builtin_amdgcn_mfma_f32_16x16x32_bf16

__device__ inline unsigned short f2b(float f) {
  union { float f; unsigned int u; } x; x.f = f;
  unsigned int u = x.u;
  return (unsigned short)((u + 0x7FFFu + ((u >> 16) & 1u)) >> 16);
}
__device__ inline float bfu(unsigned int us) {
  union { unsigned int u; float f; } x; x.u = (us & 0xFFFFu) << 16;
  return x.f;
}
__device__ inline void sp3(float x, unsigned short& h, unsigned short& m, unsigned short& l) {
  h = f2b(x);
  float r1 = x - bfu(h);
  m = f2b(r1);
  l = f2b(r1 - bfu(m));
}
// direct global->LDS 16B copy (wave-uniform LDS base + lane*16; per-lane source)
__device__ inline void gld16(const unsigned short* g, unsigned short* l) {
  __builtin_amdgcn_global_load_lds(
      (const __attribute__((address_space(1))) void*)g,
      (__attribute__((address_space(3))) void*)l, 16, 0, 0);
}
// XOR swizzle in float4 units (involution within each 8-slot group)
__device__ inline int swzF(int F) { return F ^ ((F >> 3) & 7); }

#define E_P3  0   // Q/K proj -> 3-plane head-scatter [pl][hz][n][hd]
#define E_V3  1   // V proj   -> 3-plane [pl][hz][hd][m]
#define E_Y3  3   // merge    -> 3-plane msg [pl][mb][2048][256]
#define E_H   4   // W1       -> fp32 hbuf [mb][2048][512]
#define E_RES 5   // W2       -> fp32 residual add into descT (global sb)

// ---------------------------------------------------------------------------
// 3-plane bf16 MFMA GEMM (fp32-class): C = A*B^T, K-contig operands, planes at
// +aps/+2aps (A) and +bps/+2bps (B; B2 planes at +b2ps). 6 cross-terms.
// Tile 64x64, BK=64, 4 waves (2x2 of 32x32). LDS XOR-swizzled via pre-swizzled
// global source + global_load_lds.
// ---------------------------------------------------------------------------
template <int EPI>
__global__ __launch_bounds__(256) void t3_k(
    const unsigned short* __restrict__ A, long aps,
    const unsigned short* __restrict__ B, long bps,
    const unsigned short* __restrict__ B2, long b2ps,
    const float* __restrict__ bias,
    void* __restrict__ out,
    const unsigned char* __restrict__ masks,
    int K, int lda, int ldb, int ksplit, long sps,
    int zbase, int xorv, int selfl, int yoff) {
  const int t = threadIdx.x;
  const int z = blockIdx.z;
  const int zg = zbase + z;
  long aoff = 0, boff = 0, b2off = 0;
  if constexpr (EPI == E_P3 || EPI == E_V3) {
    boff = (long)z * 524288;                         // desc3 per-sb
  } else if constexpr (EPI == E_Y3) {
    boff = (long)zg * 524288;                        // att3 global sb
  } else if constexpr (EPI == E_H) {
    boff = (long)zg * 524288;                        // desc3 global sb
    b2off = (long)z * 524288;                        // msg3 local sb
  } else {                                           // E_RES
    boff = (long)z * 1048576;                        // hB3 local sb
  }
  const int n0 = blockIdx.x * 64;
  const int m0 = blockIdx.y * 64;

  __shared__ __align__(16) unsigned short As[3][64 * 64];
  __shared__ __align__(16) unsigned short Bs[3][64 * 64];

  const int w = t >> 6;
  const int L = t & 63;
  const int wm = (w & 1) * 32, wn = (w >> 1) * 32;
  const int lr = t & 15, lk = (t >> 4) & 3;
  const int swr = (lr & 7) << 3;                 // read-side XOR (units: shorts)
  const int grow = (L >> 3);                     // row within 8-row group
  const int gj = L & 7;                          // chunk within row

  f32x4 acc[2][2];
#pragma unroll
  for (int i = 0; i < 2; ++i)
#pragma unroll
    for (int j = 0; j < 2; ++j) acc[i][j] = (f32x4){0.f, 0.f, 0.f, 0.f};

  for (int k0 = 0; k0 < K; k0 += 64) {
    const unsigned short* Bsel;
    long bo, bp;
    int kb;
    if (k0 < ksplit) { Bsel = B; bo = boff; bp = bps; kb = k0; }
    else             { Bsel = B2; bo = b2off; bp = b2ps; kb = k0 - ksplit; }
    if (k0) __syncthreads();
#pragma unroll
    for (int pl = 0; pl < 3; ++pl) {
      const unsigned short* Ap = A + (long)pl * aps + aoff;
      const unsigned short* Bp = Bsel + (long)pl * bp + bo;
#pragma unroll
      for (int c = 0; c < 2; ++c) {
        const int rbase = w * 16 + c * 8;        // wave-uniform row base
        const int row = rbase + grow;
        const int colA = (gj ^ (row & 7)) << 3;  // pre-swizzled source chunk
        gld16(&Ap[(long)(m0 + row) * lda + k0 + colA], &As[pl][rbase * 64]);
        gld16(&Bp[(long)(n0 + row) * ldb + kb + colA], &Bs[pl][rbase * 64]);
      }
    }
    __syncthreads();
#pragma unroll
    for (int kk = 0; kk < 2; ++kk) {
      bf16x8 af[3][2], bf[3][2];
#pragma unroll
      for (int pl = 0; pl < 3; ++pl)
#pragma unroll
        for (int mi = 0; mi < 2; ++mi) {
          af[pl][mi] = *(const bf16x8*)&As[pl][(wm + mi * 16 + lr) * 64 + ((kk * 32 + lk * 8) ^ swr)];
          bf[pl][mi] = *(const bf16x8*)&Bs[pl][(wn + mi * 16 + lr) * 64 + ((kk * 32 + lk * 8) ^ swr)];
        }
#pragma unroll
      for (int mi = 0; mi < 2; ++mi)
#pragma unroll
        for (int ni = 0; ni < 2; ++ni) {
          f32x4 c = acc[mi][ni];
          c = MFMA16(af[2][mi], bf[0][ni], c, 0, 0, 0);
          c = MFMA16(af[0][mi], bf[2][ni], c, 0, 0, 0);
          c = MFMA16(af[1][mi], bf[1][ni], c, 0, 0, 0);
          c = MFMA16(af[1][mi], bf[0][ni], c, 0, 0, 0);
          c = MFMA16(af[0][mi], bf[1][ni], c, 0, 0, 0);
          c = MFMA16(af[0][mi], bf[0][ni], c, 0, 0, 0);
          acc[mi][ni] = c;
        }
    }
  }

#pragma unroll
  for (int mi = 0; mi < 2; ++mi) {
#pragma unroll
    for (int ni = 0; ni < 2; ++ni) {
      f32x4 a = acc[mi][ni];
      const int cM = m0 + wm + mi * 16 + lk * 4;
      const int pN = n0 + wn + ni * 16 + lr;
      if constexpr (EPI == E_P3) {
        float4 bv4 = *(const float4*)&bias[cM];
        float bb[4] = {bv4.x, bv4.y, bv4.z, bv4.w};
        unsigned short* o = (unsigned short*)out;
        const long b0 = (long)z * 524288 + (long)pN * 64 + (cM >> 2);
#pragma unroll
        for (int r = 0; r < 4; ++r) {
          unsigned short h_, m_, l_;
          sp3(a[r] + bb[r], h_, m_, l_);
          const long ad = b0 + (long)r * 131072;
          o[ad] = h_; o[ad + 2097152] = m_; o[ad + 4194304] = l_;
        }
      } else if constexpr (EPI == E_V3) {
        float4 bv4 = *(const float4*)&bias[cM];
        float bb[4] = {bv4.x, bv4.y, bv4.z, bv4.w};
        unsigned short* o = (unsigned short*)out;
        const long b0 = (long)z * 524288 + (long)(cM >> 2) * 2048 + pN;
#pragma unroll
        for (int r = 0; r < 4; ++r) {
          unsigned short h_, m_, l_;
          sp3(a[r] + bb[r], h_, m_, l_);
          const long ad = b0 + (long)r * 131072;
          o[ad] = h_; o[ad + 2097152] = m_; o[ad + 4194304] = l_;
        }
      } else if constexpr (EPI == E_Y3) {
        float4 bv4 = *(const float4*)&bias[cM];
        float bb[4] = {bv4.x, bv4.y, bv4.z, bv4.w};
        unsigned short* o = (unsigned short*)out;
        ushort4 h4, m4, l4;
        unsigned short* hp = (unsigned short*)&h4;
        unsigned short* mp = (unsigned short*)&m4;
        unsigned short* lp = (unsigned short*)&l4;
#pragma unroll
        for (int r = 0; r < 4; ++r) sp3(a[r] + bb[r], hp[r], mp[r], lp[r]);
        const long b0 = (long)z * 524288 + (long)pN * 256 + cM;
        *(ushort4*)&o[b0] = h4;
        *(ushort4*)&o[b0 + sps] = m4;
        *(ushort4*)&o[b0 + 2 * sps] = l4;
      } else if constexpr (EPI == E_H) {
        *(f32x4*)&((float*)out)[(long)z * 1048576 + (long)pN * 512 + cM] = a;
      } else {  // E_RES
        float4 bv4 = *(const float4*)&bias[cM];
        float* p = &((float*)out)[(long)zg * 524288 + (long)pN * 256 + cM];
        float4 old = *(const float4*)p;
        float4 nw;
        nw.x = old.x + a[0] + bv4.x; nw.y = old.y + a[1] + bv4.y;
        nw.z = old.z + a[2] + bv4.z; nw.w = old.w + a[3] + bv4.w;
        *(float4*)p = nw;
      }
    }
  }
}

// ---------------------------------------------------------------------------
// Wide-tile QK^T: 64(q) x 128(k) per block, K=64 single step. S bit-identical
// to the 64x64 version (same per-output accumulation order). STATS=1 also
// emits per-(row, 64-col-tile) softmax partials into pst (same 32-tile layout).
// grid (16, CH/64, 4).
// ---------------------------------------------------------------------------
template <int STATS>
__global__ __launch_bounds__(256) void s3w_k(
    const unsigned short* __restrict__ Q3, const unsigned short* __restrict__ K3,
    float* __restrict__ S, float2* __restrict__ pst,
    const unsigned char* __restrict__ masks,
    long sps, int zbase, int xorv, int selfl, int yoff) {
  const int t = threadIdx.x;
  const int z = blockIdx.z;
  const int zg = zbase + z;
  const int sb = zg >> 2, h = zg & 3;
  const long aoff = (long)zg * 131072;
  const long boff = (long)((sb ^ xorv) * 4 + h) * 131072;
  const int n0 = blockIdx.x * 128;
  const int m0 = yoff + blockIdx.y * 64;

  // unified LDS: A planes (3*4096), B planes (3*8192); epilogue overlays ST
  __shared__ __align__(16) unsigned short sh[3 * 4096 + 3 * 8192];
  unsigned short* Asp = sh;            // [pl][64*64]
  unsigned short* Bsp = sh + 12288;    // [pl][128*64]
  __shared__ unsigned int Ms[256];
  {
    const int type = selfl ? (sb >> 1) : 2 + (sb >> 1);
    const unsigned int* mw =
        (const unsigned int*)(masks + (long)type * MB_T + (long)(sb & 1) * MB_B);
    Ms[t] = mw[(long)(m0 + (t >> 2)) * 64 + (n0 >> 5) + (t & 3)];
  }

  const int w = t >> 6;
  const int L = t & 63;
  const int lr = t & 15, lk = (t >> 4) & 3;
  const int swr = (lr & 7) << 3;
  const int grow = L >> 3;
  const int gj = L & 7;
  const int wm = (w & 1) * 32, wn = (w >> 1) * 64;

  // stage (single K=64 step): A = 64 q-rows, B = 128 k-rows
#pragma unroll
  for (int pl = 0; pl < 3; ++pl) {
    const unsigned short* Ap = Q3 + (long)pl * 2097152 + aoff;
    const unsigned short* Bp = K3 + (long)pl * 2097152 + boff;
#pragma unroll
    for (int c = 0; c < 2; ++c) {
      const int rbase = w * 16 + c * 8;
      const int row = rbase + grow;
      const int colA = (gj ^ (row & 7)) << 3;
      gld16(&Ap[(long)(m0 + row) * 64 + colA], &Asp[pl * 4096 + rbase * 64]);
    }
#pragma unroll
    for (int c = 0; c < 4; ++c) {
      const int rbase = w * 32 + c * 8;
      const int row = rbase + grow;
      const int colA = (gj ^ (row & 7)) << 3;
      gld16(&Bp[(long)(n0 + row) * 64 + colA], &Bsp[pl * 8192 + rbase * 64]);
    }
  }
  __syncthreads();

  f32x4 acc[2][4];
#pragma unroll
  for (int i = 0; i < 2; ++i)
#pragma unroll
    for (int j = 0; j < 4; ++j) acc[i][j] = (f32x4){0.f, 0.f, 0.f, 0.f};

#pragma unroll
  for (int kk = 0; kk < 2; ++kk) {
    bf16x8 af[3][2];
#pragma unroll
    for (int pl = 0; pl < 3; ++pl)
#pragma unroll
      for (int mi = 0; mi < 2; ++mi)
        af[pl][mi] = *(const bf16x8*)&Asp[pl * 4096 + (wm + mi * 16 + lr) * 64 + ((kk * 32 + lk * 8) ^ swr)];
#pragma unroll
    for (int ni = 0; ni < 4; ++ni) {
      bf16x8 bfx[3];
#pragma unroll
      for (int pl = 0; pl < 3; ++pl)
        bfx[pl] = *(const bf16x8*)&Bsp[pl * 8192 + (wn + ni * 16 + lr) * 64 + ((kk * 32 + lk * 8) ^ swr)];
#pragma unroll
      for (int mi = 0; mi < 2; ++mi) {
        f32x4 c = acc[mi][ni];
        c = MFMA16(af[2][mi], bfx[0], c, 0, 0, 0);
        c = MFMA16(af[0][mi], bfx[2], c, 0, 0, 0);
        c = MFMA16(af[1][mi], bfx[1], c, 0, 0, 0);
        c = MFMA16(af[1][mi], bfx[0], c, 0, 0, 0);
        c = MFMA16(af[0][mi], bfx[1], c, 0, 0, 0);
        c = MFMA16(af[0][mi], bfx[0], c, 0, 0, 0);
        acc[mi][ni] = c;
      }
    }
  }

  // epilogue: stage 64x128 tile in LDS (ST stride 132), masked coalesced write
  __syncthreads();
  float* ST = (float*)sh;  // 64*132 floats = 33,792 B <= 73,728 B
#pragma unroll
  for (int mi = 0; mi < 2; ++mi)
#pragma unroll
    for (int ni = 0; ni < 4; ++ni)
#pragma unroll
      for (int r = 0; r < 4; ++r)
        ST[(wm + mi * 16 + lk * 4 + r) * 132 + wn + ni * 16 + lr] = acc[mi][ni][r];
  __syncthreads();
  float* o = S;
  const int CHrows = (int)(sps >> 11);
#pragma unroll
  for (int it = 0; it < 4; ++it) {
    const int row = (t >> 4) + it * 16;
    const int col = (t & 15) * 8;
    float4 v0 = *(const float4*)&ST[row * 132 + col];
    float4 v1 = *(const float4*)&ST[row * 132 + col + 4];
    const unsigned int mw = Ms[row * 4 + (col >> 5)];
    v0.x = ((mw >> ((col + 0) & 31)) & 1u) ? v0.x * 0.125f : 0.f;
    v0.y = ((mw >> ((col + 1) & 31)) & 1u) ? v0.y * 0.125f : 0.f;
    v0.z = ((mw >> ((col + 2) & 31)) & 1u) ? v0.z * 0.125f : 0.f;
    v0.w = ((mw >> ((col + 3) & 31)) & 1u) ? v0.w * 0.125f : 0.f;
    v1.x = ((mw >> ((col + 4) & 31)) & 1u) ? v1.x * 0.125f : 0.f;
    v1.y = ((mw >> ((col + 5) & 31)) & 1u) ? v1.y * 0.125f : 0.f;
    v1.z = ((mw >> ((col + 6) & 31)) & 1u) ? v1.z * 0.125f : 0.f;
    v1.w = ((mw >> ((col + 7) & 31)) & 1u) ? v1.w * 0.125f : 0.f;
    const int rloc = blockIdx.y * 64 + row;
    *(float4*)&o[(long)z * sps + (long)rloc * 2048 + n0 + col] = v0;
    *(float4*)&o[(long)z * sps + (long)rloc * 2048 + n0 + col + 4] = v1;
    if constexpr (STATS) {
      // 64-col half-tile partials via aligned 8-lane shuffle groups
      float mx8 = fmaxf(fmaxf(fmaxf(v0.x, v0.y), fmaxf(v0.z, v0.w)),
                        fmaxf(fmaxf(v1.x, v1.y), fmaxf(v1.z, v1.w)));
      mx8 = fmaxf(mx8, __shfl_xor(mx8, 1));
      mx8 = fmaxf(mx8, __shfl_xor(mx8, 2));
      mx8 = fmaxf(mx8, __shfl_xor(mx8, 4));
      float e8 = __expf(v0.x - mx8) + __expf(v0.y - mx8) +
                 __expf(v0.z - mx8) + __expf(v0.w - mx8) +
                 __expf(v1.x - mx8) + __expf(v1.y - mx8) +
                 __expf(v1.z - mx8) + __expf(v1.w - mx8);
      e8 += __shfl_xor(e8, 1);
      e8 += __shfl_xor(e8, 2);
      e8 += __shfl_xor(e8, 4);
      if ((t & 7) == 0)
        pst[((long)z * CHrows + rloc) * 32 + blockIdx.x * 2 + ((t >> 3) & 1)] =
            make_float2(mx8, e8);
    }
  }
}

// combine 32 per-tile partials -> global stats {m, 1/sum} per (head,row)
__global__ __launch_bounds__(256) void stat_k(const float2* __restrict__ pst,
                                              float2* __restrict__ stats) {
  const int idx = blockIdx.x * 256 + threadIdx.x;  // h*CH + row
  const float2* p = pst + (long)idx * 32;
  float m = p[0].x;
#pragma unroll
  for (int i = 1; i < 32; ++i) m = fmaxf(m, p[i].x);
  float s = 0.f;
#pragma unroll
  for (int i = 0; i < 32; ++i) s += p[i].y * __expf(p[i].x - m);
  stats[idx] = make_float2(m, 1.0f / s);
}

// ---------------------------------------------------------------------------
// Row-per-block softmax stats + fused exact top-k prune (r20 verified).
// ---------------------------------------------------------------------------
__global__ __launch_bounds__(256) void softmax_prune_k(
    const float* __restrict__ S, float2* __restrict__ stats,
    unsigned char* __restrict__ masks,
    int knew, int sbG, int cb, int selfl, long sps, int CH) {
  const int t = threadIdx.x;
  const int lane = t & 63;
  const int wv = t >> 6;          // wave id == head for phase 1
  const int nl = blockIdx.x;      // row

  __shared__ __align__(16) float4 pL4[4][512];  // 32 KB p-values, swizzled
  __shared__ int hist[256];
  __shared__ int wred[4];
  __shared__ int sbx[2];

  // phase 1: wave wv handles head wv
  {
    const float* row = S + (long)wv * sps + (long)nl * 2048 + lane * 32;
    float xs[32];
#pragma unroll
    for (int e = 0; e < 8; ++e) {
      float4 u = *(const float4*)(row + e * 4);
      xs[e * 4 + 0] = u.x; xs[e * 4 + 1] = u.y;
      xs[e * 4 + 2] = u.z; xs[e * 4 + 3] = u.w;
    }
    float m = xs[0];
#pragma unroll
    for (int j = 1; j < 32; ++j) m = fmaxf(m, xs[j]);
    for (int o = 32; o; o >>= 1) m = fmaxf(m, __shfl_xor(m, o));
    float s = 0.f;
#pragma unroll
    for (int j = 0; j < 32; ++j) { xs[j] = __expf(xs[j] - m); s += xs[j]; }
    for (int o = 32; o; o >>= 1) s += __shfl_xor(s, o);
    const float ri = 1.0f / s;
    if (lane == 0) stats[(long)wv * CH + nl] = make_float2(m, ri);
#pragma unroll
    for (int e = 0; e < 8; ++e) {
      float4 pv;
      pv.x = xs[e * 4 + 0] * ri; pv.y = xs[e * 4 + 1] * ri;
      pv.z = xs[e * 4 + 2] * ri; pv.w = xs[e * 4 + 3] * ri;
      pL4[wv][swzF(lane * 8 + e)] = pv;
    }
  }
  __syncthreads();

  // phase 2: thread t owns cols t*8+j
  unsigned int key[8];
  {
#pragma unroll
    for (int jj = 0; jj < 2; ++jj) {
      const int Fs = swzF(t * 2 + jj);
      float4 p0 = pL4[0][Fs];
      float4 p1 = pL4[1][Fs];
      float4 p2 = pL4[2][Fs];
      float4 p3 = pL4[3][Fs];
      float4 mm;
      mm.x = 0.25f * p0.x; mm.x += 0.25f * p1.x; mm.x += 0.25f * p2.x; mm.x += 0.25f * p3.x;
      mm.y = 0.25f * p0.y; mm.y += 0.25f * p1.y; mm.y += 0.25f * p2.y; mm.y += 0.25f * p3.y;
      mm.z = 0.25f * p0.z; mm.z += 0.25f * p1.z; mm.z += 0.25f * p2.z; mm.z += 0.25f * p3.z;
      mm.w = 0.25f * p0.w; mm.w += 0.25f * p1.w; mm.w += 0.25f * p2.w; mm.w += 0.25f * p3.w;
      key[jj * 4 + 0] = __float_as_uint(mm.x);
      key[jj * 4 + 1] = __float_as_uint(mm.y);
      key[jj * 4 + 2] = __float_as_uint(mm.z);
      key[jj * 4 + 3] = __float_as_uint(mm.w);
    }
  }

  // phase 3: block-wide radix select
  unsigned int pref = 0;
  int kneed = knew;
  for (int pass = 0; pass < 4; ++pass) {
    const int shift = 24 - pass * 8;
    hist[t] = 0;
    __syncthreads();
    const unsigned int hm = (pass == 0) ? 0u : (0xFFFFFFFFu << (shift + 8));
#pragma unroll
    for (int j = 0; j < 8; ++j) {
      unsigned int k = key[j];
      if ((k & hm) == pref) atomicAdd(&hist[(k >> shift) & 255], 1);
    }
    __syncthreads();
    const int h = hist[t];
    int s = h;
#pragma unroll
    for (int o = 1; o < 64; o <<= 1) {
      int tmp = __shfl_down(s, o);
      if (lane + o < 64) s += tmp;
    }
    if (lane == 0) wred[wv] = s;
    __syncthreads();
    int addhi = 0;
#pragma unroll
    for (int w2 = 0; w2 < 4; ++w2)
      if (w2 > wv) addhi += wred[w2];
    s += addhi;
    const int above = s - h;
    if (s >= kneed && above < kneed) { sbx[0] = t; sbx[1] = above; }
    __syncthreads();
    pref |= ((unsigned int)sbx[0]) << shift;
    kneed -= sbx[1];
    __syncthreads();
  }
  const unsigned int T = pref;
  const int take = kneed;
  int cnt = 0;
#pragma unroll
  for (int j = 0; j < 8; ++j) cnt += (key[j] == T);
  int pc = cnt;
#pragma unroll
  for (int o = 1; o < 64; o <<= 1) {
    int tmp = __shfl_up(pc, o);
    if (lane >= o) pc += tmp;
  }
  if (lane == 63) wred[wv] = pc;
  __syncthreads();
  int woff = 0;
#pragma unroll
  for (int w2 = 0; w2 < 4; ++w2)
    if (w2 < wv) woff += wred[w2];
  int base = woff + pc - cnt;
  unsigned int byte = 0;
#pragma unroll
  for (int j = 0; j < 8; ++j) {
    unsigned int k = key[j];
    int sel = 0;
    if (k > T) sel = 1;
    else if (k == T) { if (T > 0u && base < take) sel = 1; base++; }
    byte |= (unsigned int)sel << j;
  }
  const int type = selfl ? (sbG >> 1) : 2 + (sbG >> 1);
  unsigned char* mb = masks + (long)type * MB_T + (long)(sbG & 1) * MB_B;
  mb[(long)(cb + nl) * MB_ROW + t] = (unsigned char)byte;
}

// ---------------------------------------------------------------------------
// PV: part[ks][h][n][64] (fp32, hd-contiguous -> full-cacheline float4 writes)
// = P x V3, with P computed on the fly from raw S + stats.
// ---------------------------------------------------------------------------
__global__ __launch_bounds__(256) void pv3_k(
    const unsigned short* __restrict__ V3, const float* __restrict__ S, long sps,
    const float2* __restrict__ stats, int CH,
    float* __restrict__ part, int zbase, int xorv) {
  const int t = threadIdx.x;
  const int h = blockIdx.z;
  const int kseg = blockIdx.y;
  const int n0 = blockIdx.x * 64;
  const int sb = zbase >> 2;
  const unsigned short* Vb = V3 + (long)((sb ^ xorv) * 4 + h) * 131072;
  const float* Sp = S + (long)h * sps;
  const float2* sth = stats + (long)h * CH;

  __shared__ __align__(16) unsigned short Bs[3][64 * 64];

  const int w = t >> 6;
  const int wm = (w & 1) * 32, wn = (w >> 1) * 32;
  const int lr = t & 15, lk = (t >> 4) & 3;
  const int srow = t >> 3, scol = (t & 7) * 8;
  const int sws = scol ^ ((srow & 7) << 3);
  const int swr = (lr & 7) << 3;

  f32x4 acc[2][2];
#pragma unroll
  for (int i = 0; i < 2; ++i)
#pragma unroll
    for (int j = 0; j < 2; ++j) acc[i][j] = (f32x4){0.f, 0.f, 0.f, 0.f};

  const int kbeg = kseg * 256;
  const float2 st0 = sth[n0 + srow];
  const float2 st1 = sth[n0 + 32 + srow];
  const float* srcA = &Sp[(long)(n0 + srow) * 2048 + kbeg + scol];
  const float* srcB = &Sp[(long)(n0 + 32 + srow) * 2048 + kbeg + scol];

  float4 c0a = *(const float4*)srcA;
  float4 c0b = *(const float4*)(srcA + 4);
  float4 c1a = *(const float4*)srcB;
  float4 c1b = *(const float4*)(srcB + 4);

#pragma unroll
  for (int ki = 0; ki < 4; ++ki) {
    const int k0 = kbeg + ki * 64;
    float4 n0a, n0b, n1a, n1b;
    if (ki < 3) {
      const int off = (ki + 1) * 64;
      n0a = *(const float4*)(srcA + off);
      n0b = *(const float4*)(srcA + off + 4);
      n1a = *(const float4*)(srcB + off);
      n1b = *(const float4*)(srcB + off + 4);
    }
    if (ki) __syncthreads();
    {
      float xs[8] = {c0a.x, c0a.y, c0a.z, c0a.w, c0b.x, c0b.y, c0b.z, c0b.w};
      ushort4 hq[2], mq[2], lq[2];
      unsigned short* hp = (unsigned short*)hq;
      unsigned short* mp = (unsigned short*)mq;
      unsigned short* lp = (unsigned short*)lq;
#pragma unroll
      for (int j = 0; j < 8; ++j) {
        float p = __expf(xs[j] - st0.x) * st0.y;
        sp3(p, hp[j], mp[j], lp[j]);
      }
      *(ushort4*)&Bs[0][srow * 64 + sws] = hq[0];
      *(ushort4*)&Bs[0][srow * 64 + sws + 4] = hq[1];
      *(ushort4*)&Bs[1][srow * 64 + sws] = mq[0];
      *(ushort4*)&Bs[1][srow * 64 + sws + 4] = mq[1];
      *(ushort4*)&Bs[2][srow * 64 + sws] = lq[0];
      *(ushort4*)&Bs[2][srow * 64 + sws + 4] = lq[1];
    }
    {
      float xs[8] = {c1a.x, c1a.y, c1a.z, c1a.w, c1b.x, c1b.y, c1b.z, c1b.w};
      ushort4 hq[2], mq[2], lq[2];
      unsigned short* hp = (unsigned short*)hq;
      unsigned short* mp = (unsigned short*)mq;
      unsigned short* lp = (unsigned short*)lq;
#pragma unroll
      for (int j = 0; j < 8; ++j) {
        float p = __expf(xs[j] - st1.x) * st1.y;
        sp3(p, hp[j], mp[j], lp[j]);
      }
      const int rr = 32 + srow;
      *(ushort4*)&Bs[0][rr * 64 + sws] = hq[0];
      *(ushort4*)&Bs[0][rr * 64 + sws + 4] = hq[1];
      *(ushort4*)&Bs[1][rr * 64 + sws] = mq[0];
      *(ushort4*)&Bs[1][rr * 64 + sws + 4] = mq[1];
      *(ushort4*)&Bs[2][rr * 64 + sws] = lq[0];
      *(ushort4*)&Bs[2][rr * 64 + sws + 4] = lq[1];
    }
    __syncthreads();
#pragma unroll
    for (int kk = 0; kk < 2; ++kk) {
      bf16x8 af[3][2], bf[3][2];
#pragma unroll
      for (int pl = 0; pl < 3; ++pl) {
#pragma unroll
        for (int mi = 0; mi < 2; ++mi) {
          af[pl][mi] = *(const bf16x8*)&Vb[(long)pl * 2097152 +
                                           (long)(wm + mi * 16 + lr) * 2048 + k0 + kk * 32 + lk * 8];
          bf[pl][mi] = *(const bf16x8*)&Bs[pl][(wn + mi * 16 + lr) * 64 + ((kk * 32 + lk * 8) ^ swr)];
        }
      }
#pragma unroll
      for (int mi = 0; mi < 2; ++mi)
#pragma unroll
        for (int ni = 0; ni < 2; ++ni) {
          f32x4 c = acc[mi][ni];
          c = MFMA16(af[2][mi], bf[0][ni], c, 0, 0, 0);
          c = MFMA16(af[0][mi], bf[2][ni], c, 0, 0, 0);
          c = MFMA16(af[1][mi], bf[1][ni], c, 0, 0, 0);
          c = MFMA16(af[1][mi], bf[0][ni], c, 0, 0, 0);
          c = MFMA16(af[0][mi], bf[1][ni], c, 0, 0, 0);
          c = MFMA16(af[0][mi], bf[0][ni], c, 0, 0, 0);
          acc[mi][ni] = c;
        }
    }
    if (ki < 3) { c0a = n0a; c0b = n0b; c1a = n1a; c1b = n1b; }
  }

  float* pp = part + (((long)kseg * 4 + h) * CH) * 64;
#pragma unroll
  for (int mi = 0; mi < 2; ++mi) {
#pragma unroll
    for (int ni = 0; ni < 2; ++ni) {
      const int cM = wm + mi * 16 + lk * 4;
      const int pN = n0 + wn + ni * 16 + lr;
      *(f32x4*)&pp[(long)pN * 64 + cM] = acc[mi][ni];
    }
  }
}

// sum 8 ksegs over part[ks][h][n][64]; assemble c = hd*4+h; 3-plane att3 write
__global__ __launch_bounds__(256) void comb_k(const float* __restrict__ part,
                                              unsigned short* __restrict__ att3,
                                              int CH, int sb, int cb) {
  const int q = threadIdx.x & 63;        // hd
  const int g = threadIdx.x >> 6;        // row subgroup
  const int nl = blockIdx.x * 4 + g;
  float s[4] = {0.f, 0.f, 0.f, 0.f};
#pragma unroll
  for (int ks = 0; ks < 8; ++ks)
#pragma unroll
    for (int h = 0; h < 4; ++h)
      s[h] += part[(((long)ks * 4 + h) * CH + nl) * 64 + q];
  ushort4 h4, m4, l4;
  unsigned short* hp = (unsigned short*)&h4;
  unsigned short* mp = (unsigned short*)&m4;
  unsigned short* lp = (unsigned short*)&l4;
#pragma unroll
  for (int h = 0; h < 4; ++h) sp3(s[h], hp[h], mp[h], lp[h]);
  const long base = (long)sb * 524288 + (long)(cb + nl) * 256 + 4 * q;
  *(ushort4*)&att3[base] = h4;
  *(ushort4*)&att3[base + 2097152] = m4;
  *(ushort4*)&att3[base + 4194304] = l4;
}

// ---------------------------------------------------------------------------
// coalesced 3-phase instance-norm: A partial sums, B stats, C normalize+split
// ---------------------------------------------------------------------------
__global__ __launch_bounds__(256) void inormA_k(const float* __restrict__ H,
                                                float* __restrict__ partial) {
  const int seg = blockIdx.x, sbl = blockIdx.y;
  const float* hp = H + (long)sbl * 1048576;
  const int t = threadIdx.x;
  float s0 = 0.f, q0 = 0.f, s1 = 0.f, q1 = 0.f;
  const int r0 = seg * 64;
  for (int r = r0; r < r0 + 64; ++r) {
    float x0 = hp[(long)r * 512 + t];
    float x1 = hp[(long)r * 512 + t + 256];
    s0 += x0; q0 = fmaf(x0, x0, q0);
    s1 += x1; q1 = fmaf(x1, x1, q1);
  }
  float* pp = partial + ((long)sbl * 32 + seg) * 1024;
  pp[t] = s0; pp[t + 256] = s1;
  pp[512 + t] = q0; pp[512 + t + 256] = q1;
}

__global__ __launch_bounds__(256) void inormB_k(const float* __restrict__ partial,
                                                float* __restrict__ stats2) {
  const int sbl = blockIdx.x;
  const int t = threadIdx.x;
  const float* pp = partial + (long)sbl * 32768;
  float a0 = 0.f, b0 = 0.f, a1 = 0.f, b1 = 0.f;
  for (int seg = 0; seg < 32; ++seg) {
    const float* p = pp + seg * 1024;
    a0 += p[t]; a1 += p[t + 256];
    b0 += p[512 + t]; b1 += p[512 + t + 256];
  }
  float mu0 = a0 * (1.f / 2048.f);
  float mu1 = a1 * (1.f / 2048.f);
  float rs0 = rsqrtf(b0 * (1.f / 2048.f) - mu0 * mu0 + 1e-5f);
  float rs1 = rsqrtf(b1 * (1.f / 2048.f) - mu1 * mu1 + 1e-5f);
  float* st = stats2 + (long)sbl * 1024;
  st[t] = mu0; st[t + 256] = mu1;
  st[512 + t] = rs0; st[512 + t + 256] = rs1;
}

__global__ __launch_bounds__(256) void inormC_k(const float* __restrict__ H,
                                                const float* __restrict__ stats2,
                                                unsigned short* __restrict__ HB,
                                                long hps) {
  const int seg = blockIdx.x, sbl = blockIdx.y;
  const float* hp = H + (long)sbl * 1048576;
  unsigned short* hb = HB + (long)sbl * 1048576;
  const float* st = stats2 + (long)sbl * 1024;
  const int t = threadIdx.x;
  const float mu0 = st[t], mu1 = st[t + 256];
  const float rs0 = st[512 + t], rs1 = st[512 + t + 256];
  const int r0 = seg * 64;
  for (int r = r0; r < r0 + 64; ++r) {
    float x0 = hp[(long)r * 512 + t];
    float x1 = hp[(long)r * 512 + t + 256];
    float o0 = (x0 - mu0) * rs0; o0 = o0 > 0.f ? o0 : 0.f;
    float o1 = (x1 - mu1) * rs1; o1 = o1 > 0.f ? o1 : 0.f;
    unsigned short h_, m_, l_;
    sp3(o0, h_, m_, l_);
    const long ad0 = (long)r * 512 + t;
    hb[ad0] = h_; hb[ad0 + hps] = m_; hb[ad0 + 2 * hps] = l_;
    sp3(o1, h_, m_, l_);
    const long ad1 = ad0 + 256;
    hb[ad1] = h_; hb[ad1 + hps] = m_; hb[ad1 + 2 * hps] = l_;
  }
}

// all 6 weight blocks of one layer -> 3-plane wbuf
__global__ __launch_bounds__(256) void split6_k(
    const float* __restrict__ q, const float* __restrict__ k,
    const float* __restrict__ v, const float* __restrict__ m,
    const float* __restrict__ w1, const float* __restrict__ w2,
    unsigned short* __restrict__ dst) {
  long i = ((long)blockIdx.x * 256 + threadIdx.x) * 4;
  const float* src;
  long off, base, ps;
  if (i < 262144) {
    int sel = (int)(i >> 16);
    src = sel == 0 ? q : sel == 1 ? k : sel == 2 ? v : m;
    off = i & 65535; base = (long)sel * 196608; ps = 65536;
  } else if (i < 524288) {
    src = w1; off = i - 262144; base = 786432; ps = 262144;
  } else {
    src = w2; off = i - 524288; base = 1572864; ps = 131072;
  }
  float4 vv = *(const float4*)&src[off];
  float xs[4] = {vv.x, vv.y, vv.z, vv.w};
  ushort4 h4, m4, l4;
  unsigned short* hp = (unsigned short*)&h4;
  unsigned short* mp = (unsigned short*)&m4;
  unsigned short* lp = (unsigned short*)&l4;
#pragma unroll
  for (int j = 0; j < 4; ++j) sp3(xs[j], hp[j], mp[j], lp[j]);
  *(ushort4*)&dst[base + off] = h4;
  *(ushort4*)&dst[base + ps + off] = m4;
  *(ushort4*)&dst[base + 2 * ps + off] = l4;
}

// fp32 -> 3 bf16 planes (desc)
__global__ __launch_bounds__(256) void split3_k(const float* __restrict__ src,
                                                unsigned short* __restrict__ dst,
                                                long plane, long n) {
  long i = ((long)blockIdx.x * 256 + threadIdx.x) * 4;
  if (i >= n) return;
  float4 v = *(const float4*)&src[i];
  float xs[4] = {v.x, v.y, v.z, v.w};
  ushort4 h4, m4, l4;
  unsigned short* hp = (unsigned short*)&h4;
  unsigned short* mp = (unsigned short*)&m4;
  unsigned short* lp = (unsigned short*)&l4;
#pragma unroll
  for (int j = 0; j < 4; ++j) sp3(xs[j], hp[j], mp[j], lp[j]);
  *(ushort4*)&dst[i] = h4;
  *(ushort4*)&dst[plane + i] = m4;
  *(ushort4*)&dst[2 * plane + i] = l4;
}

// in: [b][256][2048] x2 streams -> descT [sb][2048][256] fp32
__global__ __launch_bounds__(256) void tin_k(const float* __restrict__ d0,
                                             const float* __restrict__ d1,
                                             float* __restrict__ descT) {
  __shared__ float tl[32][33];
  const int sb = blockIdx.z, s = sb >> 1, b = sb & 1;
  const float* src = (s ? d1 : d0) + (long)b * 524288;
  const int p0 = blockIdx.x * 32, c0 = blockIdx.y * 32;
  const int tx = threadIdx.x & 31, ty = threadIdx.x >> 5;
#pragma unroll
  for (int i = 0; i < 4; ++i)
    tl[ty + i * 8][tx] = src[(long)(c0 + ty + i * 8) * 2048 + p0 + tx];
  __syncthreads();
#pragma unroll
  for (int i = 0; i < 4; ++i)
    descT[(long)sb * 524288 + (long)(p0 + ty + i * 8) * 256 + c0 + tx] = tl[tx][ty + i * 8];
}

// descT [sb][2048][256] -> out [s][b][256][2048]
__global__ __launch_bounds__(256) void tout_k(const float* __restrict__ descT,
                                              float* __restrict__ out) {
  __shared__ float tl[32][33];
  const int sb = blockIdx.z;
  const int p0 = blockIdx.x * 32, c0 = blockIdx.y * 32;
  const int tx = threadIdx.x & 31, ty = threadIdx.x >> 5;
#pragma unroll
  for (int i = 0; i < 4; ++i)
    tl[ty + i * 8][tx] = descT[(long)sb * 524288 + (long)(p0 + ty + i * 8) * 256 + c0 + tx];
  __syncthreads();
#pragma unroll
  for (int i = 0; i < 4; ++i)
    out[(long)sb * 524288 + (long)(c0 + ty + i * 8) * 2048 + p0 + tx] = tl[tx][ty + i * 8];
}

// ---------------------------------------------------------------------------
extern "C" void kernel_launch(void* const* d_in, const int* in_sizes, int n_in,
                              void* d_out, int out_size, void* d_ws, size_t ws_size,
                              hipStream_t stream) {
  (void)in_sizes; (void)n_in; (void)out_size;
  const float* in_d0 = (const float*)d_in[0];
  const float* in_d1 = (const float*)d_in[1];
  const float* Wq = (const float*)d_in[2];
  const float* bq = (const float*)d_in[3];
  const float* Wk = (const float*)d_in[4];
  const float* bk = (const float*)d_in[5];
  const float* Wv = (const float*)d_in[6];
  const float* bv = (const float*)d_in[7];
  const float* Wm = (const float*)d_in[8];
  const float* bm = (const float*)d_in[9];
  const float* W1 = (const float*)d_in[10];
  const float* b1 = (const float*)d_in[11];
  const float* W2 = (const float*)d_in[12];
  const float* b2 = (const float*)d_in[13];
  (void)b1;  // exact no-op through InstanceNorm (mean-subtracted)

  const long region_b = (long)ws_size - 79429632;
  const int CH = (region_b >= 40992L * 2048) ? 2048
               : (region_b >= 40992L * 1024) ? 1024 : 512;
  const int nchunks = 2048 / CH;
  const long sps = (long)CH * 2048;
  const int mb = (region_b >= 4 * 13766656L) ? 4 : (region_b >= 2 * 13766656L) ? 2 : 1;

  uint8_t* w = (uint8_t*)d_ws;
  float* descT          = (float*)w;                        // 8,388,608
  unsigned short* desc3 = (unsigned short*)(w + 8388608);   // [3][4][2048][256]
  unsigned short* Q3    = (unsigned short*)(w + 20971520);  // [3][16][2048][64]
  unsigned short* K3    = (unsigned short*)(w + 33554432);
  unsigned short* V3    = (unsigned short*)(w + 46137344);  // [3][16][64][2048]
  unsigned short* att3  = (unsigned short*)(w + 58720256);  // [3][4][2048][256]
  unsigned short* wbuf  = (unsigned short*)(w + 71303168);  // 3,932,160 B
  unsigned char* masks  = w + 75235328;                     // 4,194,304
  uint8_t* region       = w + 79429632;
  float* S              = (float*)region;                          // [4][CH][2048] f32
  float* part           = (float*)(region + (long)CH * 32768);     // [8][4][CH][64] f32
  float2* pst           = (float2*)part;                           // [4][CH][32] overlay (dead before pv3)
  float2* stats         = (float2*)(region + (long)CH * 32768 + (long)CH * 8192); // [4][CH]
  unsigned short* msg3  = (unsigned short*)region;                           // [3][mb][2048][256]
  float* hbuf           = (float*)(region + (long)mb * 3145728);             // [mb][2048][512] f32
  unsigned short* hB3   = (unsigned short*)(region + (long)mb * 7340032);    // [3][mb][2048][512]
  float* inpart         = (float*)(region + (long)mb * 13631488);            // [mb][32][2][512]
  float* instats        = (float*)(region + (long)mb * 13631488 + (long)mb * 131072); // [mb][2][512]

  const unsigned short* wq3 = wbuf;
  const unsigned short* wk3 = wbuf + 196608;
  const unsigned short* wv3 = wbuf + 393216;
  const unsigned short* wm3 = wbuf + 589824;
  const unsigned short* w13 = wbuf + 786432;
  const unsigned short* w23 = wbuf + 1572864;

  tin_k<<<dim3(64, 8, 4), 256, 0, stream>>>(in_d0, in_d1, descT);
  hipMemsetAsync(masks, 0xFF, 4 * MB_T, stream);

  for (int l = 0; l < 6; ++l) {
    const int selfl = (l % 2 == 0);
    const int xorv = selfl ? 0 : 2;
    const int knew = (l < 2) ? 1024 : (l < 4) ? 512 : 0;

    split6_k<<<dim3(640), 256, 0, stream>>>(Wq + (long)l * 65536, Wk + (long)l * 65536,
                                            Wv + (long)l * 65536, Wm + (long)l * 65536,
                                            W1 + (long)l * 262144, W2 + (long)l * 131072,
                                            wbuf);
    split3_k<<<dim3(2048), 256, 0, stream>>>(descT, desc3, 2097152, 2097152);

    t3_k<E_P3><<<dim3(32, 4, 4), 256, 0, stream>>>(
        wq3, 65536, desc3, 2097152, nullptr, 0, bq + l * 256, Q3, nullptr,
        256, 256, 256, 1 << 30, 0, 0, 0, 0, 0);
    t3_k<E_P3><<<dim3(32, 4, 4), 256, 0, stream>>>(
        wk3, 65536, desc3, 2097152, nullptr, 0, bk + l * 256, K3, nullptr,
        256, 256, 256, 1 << 30, 0, 0, 0, 0, 0);
    t3_k<E_V3><<<dim3(32, 4, 4), 256, 0, stream>>>(
        wv3, 65536, desc3, 2097152, nullptr, 0, bv + l * 256, V3, nullptr,
        256, 256, 256, 1 << 30, 0, 0, 0, 0, 0);

    for (int sb = 0; sb < 4; ++sb) {
      for (int c = 0; c < nchunks; ++c) {
        const int cb = c * CH;
        if (knew) {
          // prune layers: wide-tile S3, combined stats+prune in one S pass
          s3w_k<0><<<dim3(16, CH / 64, 4), 256, 0, stream>>>(
              Q3, K3, S, pst, masks, sps, sb * 4, xorv, selfl, cb);
          softmax_prune_k<<<dim3(CH), 256, 0, stream>>>(
              S, stats, masks, knew, sb, cb, selfl, sps, CH);
        } else {
          // non-prune layers: wide-tile S3 with fused tile-stats, no softmax pass
          s3w_k<1><<<dim3(16, CH / 64, 4), 256, 0, stream>>>(
              Q3, K3, S, pst, masks, sps, sb * 4, xorv, selfl, cb);
          stat_k<<<dim3(4 * CH / 256), 256, 0, stream>>>(pst, stats);
        }
        pv3_k<<<dim3(CH / 64, 8, 4), 256, 0, stream>>>(V3, S, sps, stats, CH, part, sb * 4, xorv);
        comb_k<<<dim3(CH / 4), 256, 0, stream>>>(part, att3, CH, sb, cb);
      }
    }

    for (int p = 0; p < 4; p += mb) {
      t3_k<E_Y3><<<dim3(32, 4, mb), 256, 0, stream>>>(
          wm3, 65536, att3, 2097152, nullptr, 0, bm + l * 256, msg3, nullptr,
          256, 256, 256, 1 << 30, (long)mb * 524288, p, 0, 0, 0);
      t3_k<E_H><<<dim3(32, 8, mb), 256, 0, stream>>>(
          w13, 262144, desc3, 2097152, msg3, (long)mb * 524288, nullptr, hbuf, nullptr,
          512, 512, 256, 256, 0, p, 0, 0, 0);
      inormA_k<<<dim3(32, mb), 256, 0, stream>>>(hbuf, inpart);
      inormB_k<<<dim3(mb), 256, 0, stream>>>(inpart, instats);
      inormC_k<<<dim3(32, mb), 256, 0, stream>>>(hbuf, instats, hB3, (long)mb * 1048576);
      t3_k<E_RES><<<dim3(32, 4, mb), 256, 0, stream>>>(
          w23, 131072, hB3, (long)mb * 1048576, nullptr, 0, b2 + l * 256, descT, nullptr,
          512, 512, 512, 1 << 30, 0, p, 0, 0, 0);
    }
  }

  tout_k<<<dim3(64, 8, 4), 256, 0, stream>>>(descT, (float*)d_out);
}

// Round 22
// 2833.264 us; speedup vs baseline: 1.0258x; 1.0258x over previous
//
#include <hip/hip_runtime.h>
#include <hip/hip_bf16.h>
#include <stdint.h>

#define NPTS 2048
#define MB_ROW 256L
#define MB_B   ((long)NPTS * MB_ROW)
#define MB_T   (2 * MB_B)

typedef __attribute__((ext_vector_type(8))) short bf16x8;
typedef __attribute__((ext_vector_type(4))) float f32x4;
#define MFMA16 __builtin_amdgcn_mfma_f32_16x16x32_bf16

__device__ inline unsigned short f2b(float f) {
  union { float f; unsigned int u; } x; x.f = f;
  unsigned int u = x.u;
  return (unsigned short)((u + 0x7FFFu + ((u >> 16) & 1u)) >> 16);
}
__device__ inline float bfu(unsigned int us) {
  union { unsigned int u; float f; } x; x.u = (us & 0xFFFFu) << 16;
  return x.f;
}
__device__ inline void sp3(float x, unsigned short& h, unsigned short& m, unsigned short& l) {
  h = f2b(x);
  float r1 = x - bfu(h);
  m = f2b(r1);
  l = f2b(r1 - bfu(m));
}
// direct global->LDS 16B copy (wave-uniform LDS base + lane*16; per-lane source)
__device__ inline void gld16(const unsigned short* g, unsigned short* l) {
  __builtin_amdgcn_global_load_lds(
      (const __attribute__((address_space(1))) void*)g,
      (__attribute__((address_space(3))) void*)l, 16, 0, 0);
}
// XOR swizzle in float4 units (involution within each 8-slot group)
__device__ inline int swzF(int F) { return F ^ ((F >> 3) & 7); }

#define E_P3  0   // Q/K proj -> 3-plane head-scatter [pl][hz][n][hd]
#define E_V3  1   // V proj   -> 3-plane [pl][hz][hd][m]
#define E_S3  2   // QK^T     -> masked scaled fp32 S (plain)
#define E_Y3  3   // merge    -> 3-plane msg [pl][mb][2048][256]
#define E_H   4   // W1       -> fp32 hbuf [mb][2048][512]
#define E_RES 5   // W2       -> fp32 residual add into descT (global sb)
#define E_S3S 6   // QK^T     -> masked scaled fp32 S + per-tile softmax partials

// ---------------------------------------------------------------------------
// 3-plane bf16 MFMA GEMM (fp32-class): C = A*B^T, K-contig operands, planes at
// +aps/+2aps (A) and +bps/+2bps (B; B2 planes at +b2ps). 6 cross-terms.
// Tile 64x64, BK=64, 4 waves (2x2 of 32x32). LDS XOR-swizzled via pre-swizzled
// global source + global_load_lds. For E_S3S, `bias` carries the float2*
// partial-stats buffer pst[(z*CH + row)*32 + tile] = {tile max, tile sumexp}.
// ---------------------------------------------------------------------------
template <int EPI>
__global__ __launch_bounds__(256) void t3_k(
    const unsigned short* __restrict__ A, long aps,
    const unsigned short* __restrict__ B, long bps,
    const unsigned short* __restrict__ B2, long b2ps,
    const float* __restrict__ bias,
    void* __restrict__ out,
    const unsigned char* __restrict__ masks,
    int K, int lda, int ldb, int ksplit, long sps,
    int zbase, int xorv, int selfl, int yoff) {
  const int t = threadIdx.x;
  const int z = blockIdx.z;
  const int zg = zbase + z;
  long aoff = 0, boff = 0, b2off = 0;
  if constexpr (EPI == E_P3 || EPI == E_V3) {
    boff = (long)z * 524288;                         // desc3 per-sb
  } else if constexpr (EPI == E_S3 || EPI == E_S3S) {
    const int sb = zg >> 2, h = zg & 3;
    aoff = (long)zg * 131072;                        // Q head block
    boff = (long)((sb ^ xorv) * 4 + h) * 131072;     // K head block (src)
  } else if constexpr (EPI == E_Y3) {
    boff = (long)zg * 524288;                        // att3 global sb
  } else if constexpr (EPI == E_H) {
    boff = (long)zg * 524288;                        // desc3 global sb
    b2off = (long)z * 524288;                        // msg3 local sb
  } else {                                           // E_RES
    boff = (long)z * 1048576;                        // hB3 local sb
  }
  const int n0 = blockIdx.x * 64;
  const int m0 = ((EPI == E_S3 || EPI == E_S3S) ? yoff : 0) + blockIdx.y * 64;

  __shared__ __align__(16) unsigned short As[3][64 * 64];
  __shared__ __align__(16) unsigned short Bs[3][64 * 64];
  __shared__ unsigned int Ms[128];
  if constexpr (EPI == E_S3 || EPI == E_S3S) {
    if (t < 128) {
      const int sb = zg >> 2;
      const int type = selfl ? (sb >> 1) : 2 + (sb >> 1);
      const unsigned int* mw =
          (const unsigned int*)(masks + (long)type * MB_T + (long)(sb & 1) * MB_B);
      Ms[t] = mw[(long)(m0 + (t >> 1)) * 64 + (n0 >> 5) + (t & 1)];
    }
  }

  const int w = t >> 6;
  const int L = t & 63;
  const int wm = (w & 1) * 32, wn = (w >> 1) * 32;
  const int lr = t & 15, lk = (t >> 4) & 3;
  const int swr = (lr & 7) << 3;                 // read-side XOR (units: shorts)
  const int grow = (L >> 3);                     // row within 8-row group
  const int gj = L & 7;                          // chunk within row

  f32x4 acc[2][2];
#pragma unroll
  for (int i = 0; i < 2; ++i)
#pragma unroll
    for (int j = 0; j < 2; ++j) acc[i][j] = (f32x4){0.f, 0.f, 0.f, 0.f};

  for (int k0 = 0; k0 < K; k0 += 64) {
    const unsigned short* Bsel;
    long bo, bp;
    int kb;
    if (k0 < ksplit) { Bsel = B; bo = boff; bp = bps; kb = k0; }
    else             { Bsel = B2; bo = b2off; bp = b2ps; kb = k0 - ksplit; }
    if (k0) __syncthreads();
#pragma unroll
    for (int pl = 0; pl < 3; ++pl) {
      const unsigned short* Ap = A + (long)pl * aps + aoff;
      const unsigned short* Bp = Bsel + (long)pl * bp + bo;
#pragma unroll
      for (int c = 0; c < 2; ++c) {
        const int rbase = w * 16 + c * 8;        // wave-uniform row base
        const int row = rbase + grow;
        const int colA = (gj ^ (row & 7)) << 3;  // pre-swizzled source chunk
        gld16(&Ap[(long)(m0 + row) * lda + k0 + colA], &As[pl][rbase * 64]);
        gld16(&Bp[(long)(n0 + row) * ldb + kb + colA], &Bs[pl][rbase * 64]);
      }
    }
    __syncthreads();
#pragma unroll
    for (int kk = 0; kk < 2; ++kk) {
      bf16x8 af[3][2], bf[3][2];
#pragma unroll
      for (int pl = 0; pl < 3; ++pl)
#pragma unroll
        for (int mi = 0; mi < 2; ++mi) {
          af[pl][mi] = *(const bf16x8*)&As[pl][(wm + mi * 16 + lr) * 64 + ((kk * 32 + lk * 8) ^ swr)];
          bf[pl][mi] = *(const bf16x8*)&Bs[pl][(wn + mi * 16 + lr) * 64 + ((kk * 32 + lk * 8) ^ swr)];
        }
#pragma unroll
      for (int mi = 0; mi < 2; ++mi)
#pragma unroll
        for (int ni = 0; ni < 2; ++ni) {
          f32x4 c = acc[mi][ni];
          c = MFMA16(af[2][mi], bf[0][ni], c, 0, 0, 0);
          c = MFMA16(af[0][mi], bf[2][ni], c, 0, 0, 0);
          c = MFMA16(af[1][mi], bf[1][ni], c, 0, 0, 0);
          c = MFMA16(af[1][mi], bf[0][ni], c, 0, 0, 0);
          c = MFMA16(af[0][mi], bf[1][ni], c, 0, 0, 0);
          c = MFMA16(af[0][mi], bf[0][ni], c, 0, 0, 0);
          acc[mi][ni] = c;
        }
    }
  }

  if constexpr (EPI == E_S3 || EPI == E_S3S) {
    __syncthreads();
    float* ST = (float*)&As[0][0];  // [64][68]
#pragma unroll
    for (int mi = 0; mi < 2; ++mi)
#pragma unroll
      for (int ni = 0; ni < 2; ++ni)
#pragma unroll
        for (int r = 0; r < 4; ++r)
          ST[(wm + mi * 16 + lk * 4 + r) * 68 + wn + ni * 16 + lr] = acc[mi][ni][r];
    __syncthreads();
    float* o = (float*)out;
#pragma unroll
    for (int it = 0; it < 4; ++it) {
      const int row = (t >> 4) + it * 16;
      const int col = (t & 15) * 4;
      float4 vv = *(const float4*)&ST[row * 68 + col];
      const unsigned int mw = Ms[row * 2 + (col >> 5)];
      vv.x = ((mw >> ((col + 0) & 31)) & 1u) ? vv.x * 0.125f : 0.f;
      vv.y = ((mw >> ((col + 1) & 31)) & 1u) ? vv.y * 0.125f : 0.f;
      vv.z = ((mw >> ((col + 2) & 31)) & 1u) ? vv.z * 0.125f : 0.f;
      vv.w = ((mw >> ((col + 3) & 31)) & 1u) ? vv.w * 0.125f : 0.f;
      const int rloc = blockIdx.y * 64 + row;
      *(float4*)&o[(long)z * sps + (long)rloc * 2048 + n0 + col] = vv;
      if constexpr (EPI == E_S3S) {
        // per-(row, col-tile) softmax partials over the masked tile
        float2* pst = (float2*)const_cast<float*>(bias);
        const int CHrows = (int)(sps >> 11);
        float mx4 = fmaxf(fmaxf(vv.x, vv.y), fmaxf(vv.z, vv.w));
#pragma unroll
        for (int oo = 1; oo < 16; oo <<= 1) mx4 = fmaxf(mx4, __shfl_xor(mx4, oo));
        float e4 = __expf(vv.x - mx4) + __expf(vv.y - mx4) +
                   __expf(vv.z - mx4) + __expf(vv.w - mx4);
#pragma unroll
        for (int oo = 1; oo < 16; oo <<= 1) e4 += __shfl_xor(e4, oo);
        if ((t & 15) == 0)
          pst[((long)z * CHrows + rloc) * 32 + blockIdx.x] = make_float2(mx4, e4);
      }
    }
    return;
  }

#pragma unroll
  for (int mi = 0; mi < 2; ++mi) {
#pragma unroll
    for (int ni = 0; ni < 2; ++ni) {
      f32x4 a = acc[mi][ni];
      const int cM = m0 + wm + mi * 16 + lk * 4;
      const int pN = n0 + wn + ni * 16 + lr;
      if constexpr (EPI == E_P3) {
        float4 bv4 = *(const float4*)&bias[cM];
        float bb[4] = {bv4.x, bv4.y, bv4.z, bv4.w};
        unsigned short* o = (unsigned short*)out;
        const long b0 = (long)z * 524288 + (long)pN * 64 + (cM >> 2);
#pragma unroll
        for (int r = 0; r < 4; ++r) {
          unsigned short h_, m_, l_;
          sp3(a[r] + bb[r], h_, m_, l_);
          const long ad = b0 + (long)r * 131072;
          o[ad] = h_; o[ad + 2097152] = m_; o[ad + 4194304] = l_;
        }
      } else if constexpr (EPI == E_V3) {
        float4 bv4 = *(const float4*)&bias[cM];
        float bb[4] = {bv4.x, bv4.y, bv4.z, bv4.w};
        unsigned short* o = (unsigned short*)out;
        const long b0 = (long)z * 524288 + (long)(cM >> 2) * 2048 + pN;
#pragma unroll
        for (int r = 0; r < 4; ++r) {
          unsigned short h_, m_, l_;
          sp3(a[r] + bb[r], h_, m_, l_);
          const long ad = b0 + (long)r * 131072;
          o[ad] = h_; o[ad + 2097152] = m_; o[ad + 4194304] = l_;
        }
      } else if constexpr (EPI == E_Y3) {
        float4 bv4 = *(const float4*)&bias[cM];
        float bb[4] = {bv4.x, bv4.y, bv4.z, bv4.w};
        unsigned short* o = (unsigned short*)out;
        ushort4 h4, m4, l4;
        unsigned short* hp = (unsigned short*)&h4;
        unsigned short* mp = (unsigned short*)&m4;
        unsigned short* lp = (unsigned short*)&l4;
#pragma unroll
        for (int r = 0; r < 4; ++r) sp3(a[r] + bb[r], hp[r], mp[r], lp[r]);
        const long b0 = (long)z * 524288 + (long)pN * 256 + cM;
        *(ushort4*)&o[b0] = h4;
        *(ushort4*)&o[b0 + sps] = m4;
        *(ushort4*)&o[b0 + 2 * sps] = l4;
      } else if constexpr (EPI == E_H) {
        *(f32x4*)&((float*)out)[(long)z * 1048576 + (long)pN * 512 + cM] = a;
      } else {  // E_RES
        float4 bv4 = *(const float4*)&bias[cM];
        float* p = &((float*)out)[(long)zg * 524288 + (long)pN * 256 + cM];
        float4 old = *(const float4*)p;
        float4 nw;
        nw.x = old.x + a[0] + bv4.x; nw.y = old.y + a[1] + bv4.y;
        nw.z = old.z + a[2] + bv4.z; nw.w = old.w + a[3] + bv4.w;
        *(float4*)p = nw;
      }
    }
  }
}

// combine 32 per-tile partials -> global stats {m, 1/sum} per (head,row)
__global__ __launch_bounds__(256) void stat_k(const float2* __restrict__ pst,
                                              float2* __restrict__ stats) {
  const int idx = blockIdx.x * 256 + threadIdx.x;  // h*CH + row
  const float2* p = pst + (long)idx * 32;
  float m = p[0].x;
#pragma unroll
  for (int i = 1; i < 32; ++i) m = fmaxf(m, p[i].x);
  float s = 0.f;
#pragma unroll
  for (int i = 0; i < 32; ++i) s += p[i].y * __expf(p[i].x - m);
  stats[idx] = make_float2(m, 1.0f / s);
}

// ---------------------------------------------------------------------------
// Row-per-block softmax stats + fused exact top-k prune. Block = 1 row,
// wave w computes head w's stats; p staged in XOR-swizzled LDS; thread t
// forms mean for cols t*8+j; block-wide radix select. grid = CH.
// ---------------------------------------------------------------------------
__global__ __launch_bounds__(256) void softmax_prune_k(
    const float* __restrict__ S, float2* __restrict__ stats,
    unsigned char* __restrict__ masks,
    int knew, int sbG, int cb, int selfl, long sps, int CH) {
  const int t = threadIdx.x;
  const int lane = t & 63;
  const int wv = t >> 6;          // wave id == head for phase 1
  const int nl = blockIdx.x;      // row

  __shared__ __align__(16) float4 pL4[4][512];  // 32 KB p-values, swizzled
  __shared__ int hist[256];
  __shared__ int wred[4];
  __shared__ int sbx[2];

  // phase 1: wave wv handles head wv
  {
    const float* row = S + (long)wv * sps + (long)nl * 2048 + lane * 32;
    float xs[32];
#pragma unroll
    for (int e = 0; e < 8; ++e) {
      float4 u = *(const float4*)(row + e * 4);
      xs[e * 4 + 0] = u.x; xs[e * 4 + 1] = u.y;
      xs[e * 4 + 2] = u.z; xs[e * 4 + 3] = u.w;
    }
    float m = xs[0];
#pragma unroll
    for (int j = 1; j < 32; ++j) m = fmaxf(m, xs[j]);
    for (int o = 32; o; o >>= 1) m = fmaxf(m, __shfl_xor(m, o));
    float s = 0.f;
#pragma unroll
    for (int j = 0; j < 32; ++j) { xs[j] = __expf(xs[j] - m); s += xs[j]; }
    for (int o = 32; o; o >>= 1) s += __shfl_xor(s, o);
    const float ri = 1.0f / s;
    if (lane == 0) stats[(long)wv * CH + nl] = make_float2(m, ri);
#pragma unroll
    for (int e = 0; e < 8; ++e) {
      float4 pv;
      pv.x = xs[e * 4 + 0] * ri; pv.y = xs[e * 4 + 1] * ri;
      pv.z = xs[e * 4 + 2] * ri; pv.w = xs[e * 4 + 3] * ri;
      pL4[wv][swzF(lane * 8 + e)] = pv;
    }
  }
  __syncthreads();

  // phase 2: thread t owns cols t*8+j
  unsigned int key[8];
  {
#pragma unroll
    for (int jj = 0; jj < 2; ++jj) {
      const int Fs = swzF(t * 2 + jj);
      float4 p0 = pL4[0][Fs];
      float4 p1 = pL4[1][Fs];
      float4 p2 = pL4[2][Fs];
      float4 p3 = pL4[3][Fs];
      float4 mm;
      mm.x = 0.25f * p0.x; mm.x += 0.25f * p1.x; mm.x += 0.25f * p2.x; mm.x += 0.25f * p3.x;
      mm.y = 0.25f * p0.y; mm.y += 0.25f * p1.y; mm.y += 0.25f * p2.y; mm.y += 0.25f * p3.y;
      mm.z = 0.25f * p0.z; mm.z += 0.25f * p1.z; mm.z += 0.25f * p2.z; mm.z += 0.25f * p3.z;
      mm.w = 0.25f * p0.w; mm.w += 0.25f * p1.w; mm.w += 0.25f * p2.w; mm.w += 0.25f * p3.w;
      key[jj * 4 + 0] = __float_as_uint(mm.x);
      key[jj * 4 + 1] = __float_as_uint(mm.y);
      key[jj * 4 + 2] = __float_as_uint(mm.z);
      key[jj * 4 + 3] = __float_as_uint(mm.w);
    }
  }

  // phase 3: block-wide radix select
  unsigned int pref = 0;
  int kneed = knew;
  for (int pass = 0; pass < 4; ++pass) {
    const int shift = 24 - pass * 8;
    hist[t] = 0;
    __syncthreads();
    const unsigned int hm = (pass == 0) ? 0u : (0xFFFFFFFFu << (shift + 8));
#pragma unroll
    for (int j = 0; j < 8; ++j) {
      unsigned int k = key[j];
      if ((k & hm) == pref) atomicAdd(&hist[(k >> shift) & 255], 1);
    }
    __syncthreads();
    const int h = hist[t];
    int s = h;
#pragma unroll
    for (int o = 1; o < 64; o <<= 1) {
      int tmp = __shfl_down(s, o);
      if (lane + o < 64) s += tmp;
    }
    if (lane == 0) wred[wv] = s;
    __syncthreads();
    int addhi = 0;
#pragma unroll
    for (int w2 = 0; w2 < 4; ++w2)
      if (w2 > wv) addhi += wred[w2];
    s += addhi;
    const int above = s - h;
    if (s >= kneed && above < kneed) { sbx[0] = t; sbx[1] = above; }
    __syncthreads();
    pref |= ((unsigned int)sbx[0]) << shift;
    kneed -= sbx[1];
    __syncthreads();
  }
  const unsigned int T = pref;
  const int take = kneed;
  int cnt = 0;
#pragma unroll
  for (int j = 0; j < 8; ++j) cnt += (key[j] == T);
  int pc = cnt;
#pragma unroll
  for (int o = 1; o < 64; o <<= 1) {
    int tmp = __shfl_up(pc, o);
    if (lane >= o) pc += tmp;
  }
  if (lane == 63) wred[wv] = pc;
  __syncthreads();
  int woff = 0;
#pragma unroll
  for (int w2 = 0; w2 < 4; ++w2)
    if (w2 < wv) woff += wred[w2];
  int base = woff + pc - cnt;
  unsigned int byte = 0;
#pragma unroll
  for (int j = 0; j < 8; ++j) {
    unsigned int k = key[j];
    int sel = 0;
    if (k > T) sel = 1;
    else if (k == T) { if (T > 0u && base < take) sel = 1; base++; }
    byte |= (unsigned int)sel << j;
  }
  const int type = selfl ? (sbG >> 1) : 2 + (sbG >> 1);
  unsigned char* mb = masks + (long)type * MB_T + (long)(sbG & 1) * MB_B;
  mb[(long)(cb + nl) * MB_ROW + t] = (unsigned char)byte;
}

// ---------------------------------------------------------------------------
// PV: part[ks][h][n][64] (fp32, hd-contiguous -> full-cacheline float4 writes)
// = P x V3, with P computed on the fly from raw S + stats.
// ---------------------------------------------------------------------------
__global__ __launch_bounds__(256) void pv3_k(
    const unsigned short* __restrict__ V3, const float* __restrict__ S, long sps,
    const float2* __restrict__ stats, int CH,
    float* __restrict__ part, int zbase, int xorv) {
  const int t = threadIdx.x;
  const int h = blockIdx.z;
  const int kseg = blockIdx.y;
  const int n0 = blockIdx.x * 64;
  const int sb = zbase >> 2;
  const unsigned short* Vb = V3 + (long)((sb ^ xorv) * 4 + h) * 131072;
  const float* Sp = S + (long)h * sps;
  const float2* sth = stats + (long)h * CH;

  __shared__ __align__(16) unsigned short Bs[3][64 * 64];

  const int w = t >> 6;
  const int wm = (w & 1) * 32, wn = (w >> 1) * 32;
  const int lr = t & 15, lk = (t >> 4) & 3;
  const int srow = t >> 3, scol = (t & 7) * 8;
  const int sws = scol ^ ((srow & 7) << 3);
  const int swr = (lr & 7) << 3;

  f32x4 acc[2][2];
#pragma unroll
  for (int i = 0; i < 2; ++i)
#pragma unroll
    for (int j = 0; j < 2; ++j) acc[i][j] = (f32x4){0.f, 0.f, 0.f, 0.f};

  const int kbeg = kseg * 256;
  const float2 st0 = sth[n0 + srow];
  const float2 st1 = sth[n0 + 32 + srow];
  const float* srcA = &Sp[(long)(n0 + srow) * 2048 + kbeg + scol];
  const float* srcB = &Sp[(long)(n0 + 32 + srow) * 2048 + kbeg + scol];

  float4 c0a = *(const float4*)srcA;
  float4 c0b = *(const float4*)(srcA + 4);
  float4 c1a = *(const float4*)srcB;
  float4 c1b = *(const float4*)(srcB + 4);

#pragma unroll
  for (int ki = 0; ki < 4; ++ki) {
    const int k0 = kbeg + ki * 64;
    float4 n0a, n0b, n1a, n1b;
    if (ki < 3) {
      const int off = (ki + 1) * 64;
      n0a = *(const float4*)(srcA + off);
      n0b = *(const float4*)(srcA + off + 4);
      n1a = *(const float4*)(srcB + off);
      n1b = *(const float4*)(srcB + off + 4);
    }
    if (ki) __syncthreads();
    {
      float xs[8] = {c0a.x, c0a.y, c0a.z, c0a.w, c0b.x, c0b.y, c0b.z, c0b.w};
      ushort4 hq[2], mq[2], lq[2];
      unsigned short* hp = (unsigned short*)hq;
      unsigned short* mp = (unsigned short*)mq;
      unsigned short* lp = (unsigned short*)lq;
#pragma unroll
      for (int j = 0; j < 8; ++j) {
        float p = __expf(xs[j] - st0.x) * st0.y;
        sp3(p, hp[j], mp[j], lp[j]);
      }
      *(ushort4*)&Bs[0][srow * 64 + sws] = hq[0];
      *(ushort4*)&Bs[0][srow * 64 + sws + 4] = hq[1];
      *(ushort4*)&Bs[1][srow * 64 + sws] = mq[0];
      *(ushort4*)&Bs[1][srow * 64 + sws + 4] = mq[1];
      *(ushort4*)&Bs[2][srow * 64 + sws] = lq[0];
      *(ushort4*)&Bs[2][srow * 64 + sws + 4] = lq[1];
    }
    {
      float xs[8] = {c1a.x, c1a.y, c1a.z, c1a.w, c1b.x, c1b.y, c1b.z, c1b.w};
      ushort4 hq[2], mq[2], lq[2];
      unsigned short* hp = (unsigned short*)hq;
      unsigned short* mp = (unsigned short*)mq;
      unsigned short* lp = (unsigned short*)lq;
#pragma unroll
      for (int j = 0; j < 8; ++j) {
        float p = __expf(xs[j] - st1.x) * st1.y;
        sp3(p, hp[j], mp[j], lp[j]);
      }
      const int rr = 32 + srow;
      *(ushort4*)&Bs[0][rr * 64 + sws] = hq[0];
      *(ushort4*)&Bs[0][rr * 64 + sws + 4] = hq[1];
      *(ushort4*)&Bs[1][rr * 64 + sws] = mq[0];
      *(ushort4*)&Bs[1][rr * 64 + sws + 4] = mq[1];
      *(ushort4*)&Bs[2][rr * 64 + sws] = lq[0];
      *(ushort4*)&Bs[2][rr * 64 + sws + 4] = lq[1];
    }
    __syncthreads();
#pragma unroll
    for (int kk = 0; kk < 2; ++kk) {
      bf16x8 af[3][2], bf[3][2];
#pragma unroll
      for (int pl = 0; pl < 3; ++pl) {
#pragma unroll
        for (int mi = 0; mi < 2; ++mi) {
          af[pl][mi] = *(const bf16x8*)&Vb[(long)pl * 2097152 +
                                           (long)(wm + mi * 16 + lr) * 2048 + k0 + kk * 32 + lk * 8];
          bf[pl][mi] = *(const bf16x8*)&Bs[pl][(wn + mi * 16 + lr) * 64 + ((kk * 32 + lk * 8) ^ swr)];
        }
      }
#pragma unroll
      for (int mi = 0; mi < 2; ++mi)
#pragma unroll
        for (int ni = 0; ni < 2; ++ni) {
          f32x4 c = acc[mi][ni];
          c = MFMA16(af[2][mi], bf[0][ni], c, 0, 0, 0);
          c = MFMA16(af[0][mi], bf[2][ni], c, 0, 0, 0);
          c = MFMA16(af[1][mi], bf[1][ni], c, 0, 0, 0);
          c = MFMA16(af[1][mi], bf[0][ni], c, 0, 0, 0);
          c = MFMA16(af[0][mi], bf[1][ni], c, 0, 0, 0);
          c = MFMA16(af[0][mi], bf[0][ni], c, 0, 0, 0);
          acc[mi][ni] = c;
        }
    }
    if (ki < 3) { c0a = n0a; c0b = n0b; c1a = n1a; c1b = n1b; }
  }

  float* pp = part + (((long)kseg * 4 + h) * CH) * 64;
#pragma unroll
  for (int mi = 0; mi < 2; ++mi) {
#pragma unroll
    for (int ni = 0; ni < 2; ++ni) {
      const int cM = wm + mi * 16 + lk * 4;
      const int pN = n0 + wn + ni * 16 + lr;
      *(f32x4*)&pp[(long)pN * 64 + cM] = acc[mi][ni];
    }
  }
}

// sum 8 ksegs over part[ks][h][n][64]; assemble c = hd*4+h; 3-plane att3 write
__global__ __launch_bounds__(256) void comb_k(const float* __restrict__ part,
                                              unsigned short* __restrict__ att3,
                                              int CH, int sb, int cb) {
  const int q = threadIdx.x & 63;        // hd
  const int g = threadIdx.x >> 6;        // row subgroup
  const int nl = blockIdx.x * 4 + g;
  float s[4] = {0.f, 0.f, 0.f, 0.f};
#pragma unroll
  for (int ks = 0; ks < 8; ++ks)
#pragma unroll
    for (int h = 0; h < 4; ++h)
      s[h] += part[(((long)ks * 4 + h) * CH + nl) * 64 + q];
  ushort4 h4, m4, l4;
  unsigned short* hp = (unsigned short*)&h4;
  unsigned short* mp = (unsigned short*)&m4;
  unsigned short* lp = (unsigned short*)&l4;
#pragma unroll
  for (int h = 0; h < 4; ++h) sp3(s[h], hp[h], mp[h], lp[h]);
  const long base = (long)sb * 524288 + (long)(cb + nl) * 256 + 4 * q;
  *(ushort4*)&att3[base] = h4;
  *(ushort4*)&att3[base + 2097152] = m4;
  *(ushort4*)&att3[base + 4194304] = l4;
}

// ---------------------------------------------------------------------------
// coalesced 3-phase instance-norm: A partial sums, B stats, C normalize+split
// ---------------------------------------------------------------------------
__global__ __launch_bounds__(256) void inormA_k(const float* __restrict__ H,
                                                float* __restrict__ partial) {
  const int seg = blockIdx.x, sbl = blockIdx.y;
  const float* hp = H + (long)sbl * 1048576;
  const int t = threadIdx.x;
  float s0 = 0.f, q0 = 0.f, s1 = 0.f, q1 = 0.f;
  const int r0 = seg * 64;
  for (int r = r0; r < r0 + 64; ++r) {
    float x0 = hp[(long)r * 512 + t];
    float x1 = hp[(long)r * 512 + t + 256];
    s0 += x0; q0 = fmaf(x0, x0, q0);
    s1 += x1; q1 = fmaf(x1, x1, q1);
  }
  float* pp = partial + ((long)sbl * 32 + seg) * 1024;
  pp[t] = s0; pp[t + 256] = s1;
  pp[512 + t] = q0; pp[512 + t + 256] = q1;
}

__global__ __launch_bounds__(256) void inormB_k(const float* __restrict__ partial,
                                                float* __restrict__ stats2) {
  const int sbl = blockIdx.x;
  const int t = threadIdx.x;
  const float* pp = partial + (long)sbl * 32768;
  float a0 = 0.f, b0 = 0.f, a1 = 0.f, b1 = 0.f;
  for (int seg = 0; seg < 32; ++seg) {
    const float* p = pp + seg * 1024;
    a0 += p[t]; a1 += p[t + 256];
    b0 += p[512 + t]; b1 += p[512 + t + 256];
  }
  float mu0 = a0 * (1.f / 2048.f);
  float mu1 = a1 * (1.f / 2048.f);
  float rs0 = rsqrtf(b0 * (1.f / 2048.f) - mu0 * mu0 + 1e-5f);
  float rs1 = rsqrtf(b1 * (1.f / 2048.f) - mu1 * mu1 + 1e-5f);
  float* st = stats2 + (long)sbl * 1024;
  st[t] = mu0; st[t + 256] = mu1;
  st[512 + t] = rs0; st[512 + t + 256] = rs1;
}

__global__ __launch_bounds__(256) void inormC_k(const float* __restrict__ H,
                                                const float* __restrict__ stats2,
                                                unsigned short* __restrict__ HB,
                                                long hps) {
  const int seg = blockIdx.x, sbl = blockIdx.y;
  const float* hp = H + (long)sbl * 1048576;
  unsigned short* hb = HB + (long)sbl * 1048576;
  const float* st = stats2 + (long)sbl * 1024;
  const int t = threadIdx.x;
  const float mu0 = st[t], mu1 = st[t + 256];
  const float rs0 = st[512 + t], rs1 = st[512 + t + 256];
  const int r0 = seg * 64;
  for (int r = r0; r < r0 + 64; ++r) {
    float x0 = hp[(long)r * 512 + t];
    float x1 = hp[(long)r * 512 + t + 256];
    float o0 = (x0 - mu0) * rs0; o0 = o0 > 0.f ? o0 : 0.f;
    float o1 = (x1 - mu1) * rs1; o1 = o1 > 0.f ? o1 : 0.f;
    unsigned short h_, m_, l_;
    sp3(o0, h_, m_, l_);
    const long ad0 = (long)r * 512 + t;
    hb[ad0] = h_; hb[ad0 + hps] = m_; hb[ad0 + 2 * hps] = l_;
    sp3(o1, h_, m_, l_);
    const long ad1 = ad0 + 256;
    hb[ad1] = h_; hb[ad1 + hps] = m_; hb[ad1 + 2 * hps] = l_;
  }
}

// all 6 weight blocks of one layer -> 3-plane wbuf
__global__ __launch_bounds__(256) void split6_k(
    const float* __restrict__ q, const float* __restrict__ k,
    const float* __restrict__ v, const float* __restrict__ m,
    const float* __restrict__ w1, const float* __restrict__ w2,
    unsigned short* __restrict__ dst) {
  long i = ((long)blockIdx.x * 256 + threadIdx.x) * 4;
  const float* src;
  long off, base, ps;
  if (i < 262144) {
    int sel = (int)(i >> 16);
    src = sel == 0 ? q : sel == 1 ? k : sel == 2 ? v : m;
    off = i & 65535; base = (long)sel * 196608; ps = 65536;
  } else if (i < 524288) {
    src = w1; off = i - 262144; base = 786432; ps = 262144;
  } else {
    src = w2; off = i - 524288; base = 1572864; ps = 131072;
  }
  float4 vv = *(const float4*)&src[off];
  float xs[4] = {vv.x, vv.y, vv.z, vv.w};
  ushort4 h4, m4, l4;
  unsigned short* hp = (unsigned short*)&h4;
  unsigned short* mp = (unsigned short*)&m4;
  unsigned short* lp = (unsigned short*)&l4;
#pragma unroll
  for (int j = 0; j < 4; ++j) sp3(xs[j], hp[j], mp[j], lp[j]);
  *(ushort4*)&dst[base + off] = h4;
  *(ushort4*)&dst[base + ps + off] = m4;
  *(ushort4*)&dst[base + 2 * ps + off] = l4;
}

// fp32 -> 3 bf16 planes (desc)
__global__ __launch_bounds__(256) void split3_k(const float* __restrict__ src,
                                                unsigned short* __restrict__ dst,
                                                long plane, long n) {
  long i = ((long)blockIdx.x * 256 + threadIdx.x) * 4;
  if (i >= n) return;
  float4 v = *(const float4*)&src[i];
  float xs[4] = {v.x, v.y, v.z, v.w};
  ushort4 h4, m4, l4;
  unsigned short* hp = (unsigned short*)&h4;
  unsigned short* mp = (unsigned short*)&m4;
  unsigned short* lp = (unsigned short*)&l4;
#pragma unroll
  for (int j = 0; j < 4; ++j) sp3(xs[j], hp[j], mp[j], lp[j]);
  *(ushort4*)&dst[i] = h4;
  *(ushort4*)&dst[plane + i] = m4;
  *(ushort4*)&dst[2 * plane + i] = l4;
}

// in: [b][256][2048] x2 streams -> descT [sb][2048][256] fp32
__global__ __launch_bounds__(256) void tin_k(const float* __restrict__ d0,
                                             const float* __restrict__ d1,
                                             float* __restrict__ descT) {
  __shared__ float tl[32][33];
  const int sb = blockIdx.z, s = sb >> 1, b = sb & 1;
  const float* src = (s ? d1 : d0) + (long)b * 524288;
  const int p0 = blockIdx.x * 32, c0 = blockIdx.y * 32;
  const int tx = threadIdx.x & 31, ty = threadIdx.x >> 5;
#pragma unroll
  for (int i = 0; i < 4; ++i)
    tl[ty + i * 8][tx] = src[(long)(c0 + ty + i * 8) * 2048 + p0 + tx];
  __syncthreads();
#pragma unroll
  for (int i = 0; i < 4; ++i)
    descT[(long)sb * 524288 + (long)(p0 + ty + i * 8) * 256 + c0 + tx] = tl[tx][ty + i * 8];
}

// descT [sb][2048][256] -> out [s][b][256][2048]
__global__ __launch_bounds__(256) void tout_k(const float* __restrict__ descT,
                                              float* __restrict__ out) {
  __shared__ float tl[32][33];
  const int sb = blockIdx.z;
  const int p0 = blockIdx.x * 32, c0 = blockIdx.y * 32;
  const int tx = threadIdx.x & 31, ty = threadIdx.x >> 5;
#pragma unroll
  for (int i = 0; i < 4; ++i)
    tl[ty + i * 8][tx] = descT[(long)sb * 524288 + (long)(p0 + ty + i * 8) * 256 + c0 + tx];
  __syncthreads();
#pragma unroll
  for (int i = 0; i < 4; ++i)
    out[(long)sb * 524288 + (long)(c0 + ty + i * 8) * 2048 + p0 + tx] = tl[tx][ty + i * 8];
}

// ---------------------------------------------------------------------------
extern "C" void kernel_launch(void* const* d_in, const int* in_sizes, int n_in,
                              void* d_out, int out_size, void* d_ws, size_t ws_size,
                              hipStream_t stream) {
  (void)in_sizes; (void)n_in; (void)out_size;
  const float* in_d0 = (const float*)d_in[0];
  const float* in_d1 = (const float*)d_in[1];
  const float* Wq = (const float*)d_in[2];
  const float* bq = (const float*)d_in[3];
  const float* Wk = (const float*)d_in[4];
  const float* bk = (const float*)d_in[5];
  const float* Wv = (const float*)d_in[6];
  const float* bv = (const float*)d_in[7];
  const float* Wm = (const float*)d_in[8];
  const float* bm = (const float*)d_in[9];
  const float* W1 = (const float*)d_in[10];
  const float* b1 = (const float*)d_in[11];
  const float* W2 = (const float*)d_in[12];
  const float* b2 = (const float*)d_in[13];
  (void)b1;  // exact no-op through InstanceNorm (mean-subtracted)

  const long region_b = (long)ws_size - 79429632;
  const int CH = (region_b >= 40992L * 2048) ? 2048
               : (region_b >= 40992L * 1024) ? 1024 : 512;
  const int nchunks = 2048 / CH;
  const long sps = (long)CH * 2048;
  const int mb = (region_b >= 4 * 13766656L) ? 4 : (region_b >= 2 * 13766656L) ? 2 : 1;

  uint8_t* w = (uint8_t*)d_ws;
  float* descT          = (float*)w;                        // 8,388,608
  unsigned short* desc3 = (unsigned short*)(w + 8388608);   // [3][4][2048][256]
  unsigned short* Q3    = (unsigned short*)(w + 20971520);  // [3][16][2048][64]
  unsigned short* K3    = (unsigned short*)(w + 33554432);
  unsigned short* V3    = (unsigned short*)(w + 46137344);  // [3][16][64][2048]
  unsigned short* att3  = (unsigned short*)(w + 58720256);  // [3][4][2048][256]
  unsigned short* wbuf  = (unsigned short*)(w + 71303168);  // 3,932,160 B
  unsigned char* masks  = w + 75235328;                     // 4,194,304
  uint8_t* region       = w + 79429632;
  float* S              = (float*)region;                          // [4][CH][2048] f32
  float* part           = (float*)(region + (long)CH * 32768);     // [8][4][CH][64] f32
  float2* pst           = (float2*)part;                           // [4][CH][32] overlay (dead before pv3)
  float2* stats         = (float2*)(region + (long)CH * 32768 + (long)CH * 8192); // [4][CH]
  unsigned short* msg3  = (unsigned short*)region;                           // [3][mb][2048][256]
  float* hbuf           = (float*)(region + (long)mb * 3145728);             // [mb][2048][512] f32
  unsigned short* hB3   = (unsigned short*)(region + (long)mb * 7340032);    // [3][mb][2048][512]
  float* inpart         = (float*)(region + (long)mb * 13631488);            // [mb][32][2][512]
  float* instats        = (float*)(region + (long)mb * 13631488 + (long)mb * 131072); // [mb][2][512]

  const unsigned short* wq3 = wbuf;
  const unsigned short* wk3 = wbuf + 196608;
  const unsigned short* wv3 = wbuf + 393216;
  const unsigned short* wm3 = wbuf + 589824;
  const unsigned short* w13 = wbuf + 786432;
  const unsigned short* w23 = wbuf + 1572864;

  tin_k<<<dim3(64, 8, 4), 256, 0, stream>>>(in_d0, in_d1, descT);
  hipMemsetAsync(masks, 0xFF, 4 * MB_T, stream);

  for (int l = 0; l < 6; ++l) {
    const int selfl = (l % 2 == 0);
    const int xorv = selfl ? 0 : 2;
    const int knew = (l < 2) ? 1024 : (l < 4) ? 512 : 0;

    split6_k<<<dim3(640), 256, 0, stream>>>(Wq + (long)l * 65536, Wk + (long)l * 65536,
                                            Wv + (long)l * 65536, Wm + (long)l * 65536,
                                            W1 + (long)l * 262144, W2 + (long)l * 131072,
                                            wbuf);
    split3_k<<<dim3(2048), 256, 0, stream>>>(descT, desc3, 2097152, 2097152);

    t3_k<E_P3><<<dim3(32, 4, 4), 256, 0, stream>>>(
        wq3, 65536, desc3, 2097152, nullptr, 0, bq + l * 256, Q3, nullptr,
        256, 256, 256, 1 << 30, 0, 0, 0, 0, 0);
    t3_k<E_P3><<<dim3(32, 4, 4), 256, 0, stream>>>(
        wk3, 65536, desc3, 2097152, nullptr, 0, bk + l * 256, K3, nullptr,
        256, 256, 256, 1 << 30, 0, 0, 0, 0, 0);
    t3_k<E_V3><<<dim3(32, 4, 4), 256, 0, stream>>>(
        wv3, 65536, desc3, 2097152, nullptr, 0, bv + l * 256, V3, nullptr,
        256, 256, 256, 1 << 30, 0, 0, 0, 0, 0);

    for (int sb = 0; sb < 4; ++sb) {
      for (int c = 0; c < nchunks; ++c) {
        const int cb = c * CH;
        if (knew) {
          // prune layers: plain S3, combined stats+prune in one S pass
          t3_k<E_S3><<<dim3(32, CH / 64, 4), 256, 0, stream>>>(
              Q3, 2097152, K3, 2097152, nullptr, 0, nullptr, S, masks,
              64, 64, 64, 1 << 30, sps, sb * 4, xorv, selfl, cb);
          softmax_prune_k<<<dim3(CH), 256, 0, stream>>>(
              S, stats, masks, knew, sb, cb, selfl, sps, CH);
        } else {
          // non-prune layers: fused tile-stats in S3, no softmax pass
          t3_k<E_S3S><<<dim3(32, CH / 64, 4), 256, 0, stream>>>(
              Q3, 2097152, K3, 2097152, nullptr, 0, (const float*)pst, S, masks,
              64, 64, 64, 1 << 30, sps, sb * 4, xorv, selfl, cb);
          stat_k<<<dim3(4 * CH / 256), 256, 0, stream>>>(pst, stats);
        }
        pv3_k<<<dim3(CH / 64, 8, 4), 256, 0, stream>>>(V3, S, sps, stats, CH, part, sb * 4, xorv);
        comb_k<<<dim3(CH / 4), 256, 0, stream>>>(part, att3, CH, sb, cb);
      }
    }

    for (int p = 0; p < 4; p += mb) {
      t3_k<E_Y3><<<dim3(32, 4, mb), 256, 0, stream>>>(
          wm3, 65536, att3, 2097152, nullptr, 0, bm + l * 256, msg3, nullptr,
          256, 256, 256, 1 << 30, (long)mb * 524288, p, 0, 0, 0);
      t3_k<E_H><<<dim3(32, 8, mb), 256, 0, stream>>>(
          w13, 262144, desc3, 2097152, msg3, (long)mb * 524288, nullptr, hbuf, nullptr,
          512, 512, 256, 256, 0, p, 0, 0, 0);
      inormA_k<<<dim3(32, mb), 256, 0, stream>>>(hbuf, inpart);
      inormB_k<<<dim3(mb), 256, 0, stream>>>(inpart, instats);
      inormC_k<<<dim3(32, mb), 256, 0, stream>>>(hbuf, instats, hB3, (long)mb * 1048576);
      t3_k<E_RES><<<dim3(32, 4, mb), 256, 0, stream>>>(
          w23, 131072, hB3, (long)mb * 1048576, nullptr, 0, b2 + l * 256, descT, nullptr,
          512, 512, 512, 1 << 30, 0, p, 0, 0, 0);
    }
  }

  tout_k<<<dim3(64, 8, 4), 256, 0, stream>>>(descT, (float*)d_out);
}